// Round 3
// baseline (3372.896 us; speedup 1.0000x reference)
//
#include <hip/hip_runtime.h>
#include <hip/hip_bf16.h>

// AttenDecoder: B=64 T=32 S=64 E=128 H=256 V=32000.
// I/O fp32; compute bf16 MFMA (GEMMs) + fp32 VALU (recurrence).
// R3: k_recur rebuilt: 1024 thr/block (16 waves, 4/SIMD latency hiding),
// split-K + LDS reduce, bf16 weights (k_cvt), gi prefetch.

typedef __attribute__((ext_vector_type(8))) short  s8v;
typedef __attribute__((ext_vector_type(8))) __bf16 bf8v;
typedef __attribute__((ext_vector_type(4))) float  f4v;

#define DEV static __device__ __forceinline__

DEV ushort f2b(float f) {            // round-to-nearest-even fp32 -> bf16
  unsigned u = __float_as_uint(f);
  u += 0x7fffu + ((u >> 16) & 1u);
  return (ushort)(u >> 16);
}
DEV float b2fs(short s) { return __uint_as_float(((unsigned)(ushort)s) << 16); }

// ---------------------------------------------------------------- gather X
__global__ __launch_bounds__(256) void k_gather(
    const float* __restrict__ target, const float* __restrict__ inp,
    const float* __restrict__ posf,   const float* __restrict__ encs,
    ushort* __restrict__ X) {
  int tb = blockIdx.x; int t = tb >> 6, b = tb & 63;
  size_t xrow = (size_t)tb * 640;
  for (int c = threadIdx.x; c < 640; c += 256) {
    float v;
    if (c < 128)      v = target[((size_t)b * 32 + t) * 128 + c];
    else if (c < 256) v = posf[(size_t)b * 128 + (c - 128)];
    else if (c < 512) v = encs[(size_t)b * 256 + (c - 256)];
    else              v = inp[((size_t)b * 32 + t) * 128 + (c - 512)];
    X[xrow + c] = f2b(v);
  }
}

// ------------------------------------------- fp32 -> bf16 weight convert
// Whh 768*256 then Winw 512*256.  320 blocks * 256 thr * 4 elems.
__global__ __launch_bounds__(256) void k_cvt(
    const float* __restrict__ Whh, const float* __restrict__ Winw,
    ushort* __restrict__ Whh_b, ushort* __restrict__ Winw_b) {
  size_t j = ((size_t)blockIdx.x * 256 + threadIdx.x) * 4;
  const float* src; ushort* dst;
  if (j < 196608) { src = Whh + j; dst = Whh_b + j; }
  else            { src = Winw + (j - 196608); dst = Winw_b + (j - 196608); }
  f4v v = *(const f4v*)src;
  dst[0] = f2b(v.x); dst[1] = f2b(v.y); dst[2] = f2b(v.z); dst[3] = f2b(v.w);
}

// ------------------------------------------------- MFMA GEMM, B^T layout
template <bool RELU>
__global__ __launch_bounds__(256) void k_gemm_bt(
    const ushort* __restrict__ A, const float* __restrict__ B,
    const float* __restrict__ bias, float* __restrict__ Out,
    int N, int K) {
  __shared__ __align__(16) ushort As[128 * 40];
  __shared__ __align__(16) ushort Bs[128 * 40];
  const int m0 = blockIdx.x * 128, n0 = blockIdx.y * 128;
  const int tid = threadIdx.x;
  const int lane = tid & 63, wv = tid >> 6;
  const int wm = (wv >> 1) * 64, wn = (wv & 1) * 64;
  const int fr = lane & 15, fq = lane >> 4;
  const int srow = tid >> 2, scol = (tid & 3) * 8;
  f4v acc[4][4];
#pragma unroll
  for (int i = 0; i < 4; ++i)
#pragma unroll
    for (int j = 0; j < 4; ++j) acc[i][j] = {0.f, 0.f, 0.f, 0.f};
  const ushort* ag = A + (size_t)(m0 + srow) * K + scol;
  const float*  bg = B + (size_t)(n0 + srow) * K + scol;
  for (int k0 = 0; k0 < K; k0 += 32) {
    s8v a0 = *(const s8v*)(ag + k0);
    s8v a1 = *(const s8v*)(ag + k0 + (size_t)64 * K);
    f4v b00 = *(const f4v*)(bg + k0);
    f4v b01 = *(const f4v*)(bg + k0 + 4);
    f4v b10 = *(const f4v*)(bg + k0 + (size_t)64 * K);
    f4v b11 = *(const f4v*)(bg + k0 + (size_t)64 * K + 4);
    s8v b0, b1;
#pragma unroll
    for (int u = 0; u < 4; ++u) {
      b0[u]     = (short)f2b(b00[u]);
      b0[u + 4] = (short)f2b(b01[u]);
      b1[u]     = (short)f2b(b10[u]);
      b1[u + 4] = (short)f2b(b11[u]);
    }
    __syncthreads();
    *(s8v*)&As[srow * 40 + scol] = a0;
    *(s8v*)&As[(srow + 64) * 40 + scol] = a1;
    *(s8v*)&Bs[srow * 40 + scol] = b0;
    *(s8v*)&Bs[(srow + 64) * 40 + scol] = b1;
    __syncthreads();
    bf8v af[4], bfr[4];
#pragma unroll
    for (int i = 0; i < 4; ++i)
      af[i] = *(const bf8v*)&As[(wm + i * 16 + fr) * 40 + fq * 8];
#pragma unroll
    for (int j = 0; j < 4; ++j)
      bfr[j] = *(const bf8v*)&Bs[(wn + j * 16 + fr) * 40 + fq * 8];
#pragma unroll
    for (int i = 0; i < 4; ++i)
#pragma unroll
      for (int j = 0; j < 4; ++j)
        acc[i][j] = __builtin_amdgcn_mfma_f32_16x16x32_bf16(af[i], bfr[j],
                                                            acc[i][j], 0, 0, 0);
  }
  float bj[4];
#pragma unroll
  for (int j = 0; j < 4; ++j) bj[j] = bias[n0 + wn + j * 16 + fr];
#pragma unroll
  for (int i = 0; i < 4; ++i) {
#pragma unroll
    for (int j = 0; j < 4; ++j) {
#pragma unroll
      for (int r = 0; r < 4; ++r) {
        int gm = m0 + wm + i * 16 + fq * 4 + r;
        int gn = n0 + wn + j * 16 + fr;
        float v = acc[i][j][r] + bj[j];
        if (RELU) v = fmaxf(v, 0.f);
        Out[(size_t)gm * N + gn] = v;
      }
    }
  }
}

// -------------------------------------------------------- recurrence (R3)
// One block (1024 thr, 16 waves) per batch element b.  Split-K dot products
// with LDS reduction; bf16 weights streamed from L2; gi prefetched.
__global__ __launch_bounds__(1024) void k_recur(
    const float* __restrict__ gi_all,   // [32*64][768] fp32 (includes b_ih)
    const float* __restrict__ eo,       // [64][64][512] fp32
    const ushort* __restrict__ Whh_b,   // [768][256] bf16
    const float* __restrict__ bhh,      // [768]
    const ushort* __restrict__ Winw_b,  // [512][256] bf16
    const float* __restrict__ Winb,     // [512]
    ushort* __restrict__ feat,          // [32*64][768] bf16 (GEMM A)
    float* __restrict__ hs_out) {       // [64][256] fp32 (d_out base)
  const int b = blockIdx.x, tid = threadIdx.x;
  __shared__ __align__(16) float h[2][256];
  __shared__ __align__(16) float qv[512];
  __shared__ __align__(16) float gis[768];
  __shared__ __align__(16) float part[4][3][256];   // gh split-K partials
  __shared__ __align__(16) float qpart[2][512];
  __shared__ __align__(16) float hpart[2][512];
  __shared__ float attns[64];
  __shared__ float score[64];
  const float* eoB = eo + (size_t)b * 32768;

  float bhr = 0.f, bhz = 0.f, bhn = 0.f, qb = 0.f;
  if (tid < 256) { bhr = bhh[tid]; bhz = bhh[tid + 256]; bhn = bhh[tid + 512]; }
  if (tid < 512) qb = Winb[tid];
  if (tid < 256) h[0][tid] = 0.f;
  __syncthreads();

  const int o = tid & 255, p = tid >> 8;        // gh decomposition
  const int o2 = tid & 511, p2 = tid >> 9;      // q / h_star decomposition
  const int s16 = tid >> 4, g16 = tid & 15;     // attn decomposition
  const ushort* wr = Whh_b + (size_t)o * 256 + p * 64;
  const ushort* wz = wr + 256 * 256;
  const ushort* wn = wr + 512 * 256;
  const ushort* w0 = Winw_b + (size_t)o2 * 256 + p2 * 128;

  for (int st = 0; st < 32; ++st) {
    const float* hc = h[st & 1];
    float* hn = h[(st & 1) ^ 1];
    const float* gi_row = gi_all + ((size_t)st * 64 + b) * 768;
    float gpre = (tid < 768) ? gi_row[tid] : 0.f;   // prefetch (drains in gh)

    // ---- gh partials: rows {o, o+256, o+512}, k-slice [64p, 64p+64)
    {
      float ar = 0.f, az = 0.f, an = 0.f;
      const float* hcb = &hc[p * 64];
#pragma unroll
      for (int k = 0; k < 64; k += 8) {
        s8v r8 = *(const s8v*)(wr + k);
        s8v z8 = *(const s8v*)(wz + k);
        s8v n8 = *(const s8v*)(wn + k);
        f4v h0 = *(const f4v*)(hcb + k);
        f4v h1 = *(const f4v*)(hcb + k + 4);
        float hv[8] = {h0.x, h0.y, h0.z, h0.w, h1.x, h1.y, h1.z, h1.w};
#pragma unroll
        for (int u = 0; u < 8; ++u) {
          ar = fmaf(hv[u], b2fs(r8[u]), ar);
          az = fmaf(hv[u], b2fs(z8[u]), az);
          an = fmaf(hv[u], b2fs(n8[u]), an);
        }
      }
      part[p][0][o] = ar; part[p][1][o] = az; part[p][2][o] = an;
    }
    if (tid < 768) gis[tid] = gpre;
    __syncthreads();                                        // (1)
    // ---- gates + h update (threads 0..255)
    if (tid < 256) {
      float ar = part[0][0][tid] + part[1][0][tid] + part[2][0][tid] + part[3][0][tid] + bhr;
      float az = part[0][1][tid] + part[1][1][tid] + part[2][1][tid] + part[3][1][tid] + bhz;
      float an = part[0][2][tid] + part[1][2][tid] + part[2][2][tid] + part[3][2][tid] + bhn;
      float r = 1.f / (1.f + __expf(-(gis[tid] + ar)));
      float z = 1.f / (1.f + __expf(-(gis[tid + 256] + az)));
      float e2 = __expf(2.f * (gis[tid + 512] + r * an));   // tanh, inf-safe
      float n = 1.f - 2.f / (e2 + 1.f);
      float hnew = (1.f - z) * n + z * hc[tid];
      hn[tid] = hnew;
      if (st == 31) hs_out[(size_t)b * 256 + tid] = hnew;
    }
    __syncthreads();                                        // (2)
    // ---- q partials: row o2, k-half [128p2, 128p2+128)
    {
      float a0 = 0.f;
      const float* hb = &hn[p2 * 128];
#pragma unroll
      for (int k = 0; k < 128; k += 8) {
        s8v u8 = *(const s8v*)(w0 + k);
        f4v h0 = *(const f4v*)(hb + k);
        f4v h1 = *(const f4v*)(hb + k + 4);
        float hv[8] = {h0.x, h0.y, h0.z, h0.w, h1.x, h1.y, h1.z, h1.w};
#pragma unroll
        for (int u = 0; u < 8; ++u) a0 = fmaf(hv[u], b2fs(u8[u]), a0);
      }
      qpart[p2][o2] = a0;
    }
    __syncthreads();                                        // (3)
    if (tid < 512) qv[tid] = qpart[0][tid] + qpart[1][tid] + qb;
    __syncthreads();                                        // (4)
    // ---- attn: 16 threads per s, d-slices {g*4 + 64j}
    {
      const float* ep = eoB + s16 * 512 + g16 * 4;
      float aa = 0.f;
#pragma unroll
      for (int j = 0; j < 8; ++j) {
        f4v e4 = *(const f4v*)(ep + j * 64);
        f4v q4 = *(const f4v*)(&qv[g16 * 4 + j * 64]);
        aa = fmaf(e4.x, q4.x, aa); aa = fmaf(e4.y, q4.y, aa);
        aa = fmaf(e4.z, q4.z, aa); aa = fmaf(e4.w, q4.w, aa);
      }
      aa += __shfl_xor(aa, 8); aa += __shfl_xor(aa, 4);
      aa += __shfl_xor(aa, 2); aa += __shfl_xor(aa, 1);
      if (g16 == 0) attns[s16] = aa;
    }
    __syncthreads();                                        // (5)
    if (tid < 64) {                                         // softmax (wave 0)
      float a = attns[tid], m = a;
#pragma unroll
      for (int off = 32; off > 0; off >>= 1) m = fmaxf(m, __shfl_xor(m, off));
      float e = __expf(a - m), ss = e;
#pragma unroll
      for (int off = 32; off > 0; off >>= 1) ss += __shfl_xor(ss, off);
      score[tid] = e / ss;
    }
    __syncthreads();                                        // (6)
    // ---- h_star partials: dim o2, s-half [32p2, 32p2+32)
    {
      const float* ep = eoB + (size_t)p2 * 32 * 512 + o2;
      const float* sc = &score[p2 * 32];
      float a = 0.f;
#pragma unroll 8
      for (int s2 = 0; s2 < 32; ++s2) a = fmaf(sc[s2], ep[(size_t)s2 * 512], a);
      hpart[p2][o2] = a;
    }
    __syncthreads();                                        // (7)
    // ---- feat = bf16([h_star(512), h(256)])
    {
      size_t row = ((size_t)st * 64 + b) * 768;
      if (tid < 512)      feat[row + tid] = f2b(hpart[0][tid] + hpart[1][tid]);
      else if (tid < 768) feat[row + tid] = f2b(hn[tid - 512]);
    }
    __syncthreads();                                        // (8)
  }
}

// ----------------------------------------------- in-place log_softmax (fp32)
__global__ __launch_bounds__(256) void k_logsm(float* __restrict__ out) {
  float* p = out + (size_t)blockIdx.x * 32000;
  const int t = threadIdx.x;
  __shared__ float red[4];
  float m = 0.f;  // relu'd values are >= 0
  for (int c = t; c < 4000; c += 256) {
    f4v a = *(const f4v*)(p + (size_t)c * 8);
    f4v b = *(const f4v*)(p + (size_t)c * 8 + 4);
    m = fmaxf(m, fmaxf(fmaxf(a.x, a.y), fmaxf(a.z, a.w)));
    m = fmaxf(m, fmaxf(fmaxf(b.x, b.y), fmaxf(b.z, b.w)));
  }
#pragma unroll
  for (int off = 32; off > 0; off >>= 1) m = fmaxf(m, __shfl_xor(m, off));
  if ((t & 63) == 0) red[t >> 6] = m;
  __syncthreads();
  m = fmaxf(fmaxf(red[0], red[1]), fmaxf(red[2], red[3]));
  float s = 0.f;
  for (int c = t; c < 4000; c += 256) {
    f4v a = *(const f4v*)(p + (size_t)c * 8);
    f4v b = *(const f4v*)(p + (size_t)c * 8 + 4);
    s += __expf(a.x - m) + __expf(a.y - m) + __expf(a.z - m) + __expf(a.w - m);
    s += __expf(b.x - m) + __expf(b.y - m) + __expf(b.z - m) + __expf(b.w - m);
  }
#pragma unroll
  for (int off = 32; off > 0; off >>= 1) s += __shfl_xor(s, off);
  __syncthreads();
  if ((t & 63) == 0) red[t >> 6] = s;
  __syncthreads();
  s = red[0] + red[1] + red[2] + red[3];
  const float L = m + logf(s);
  for (int c = t; c < 4000; c += 256) {
    f4v a = *(const f4v*)(p + (size_t)c * 8);
    f4v b = *(const f4v*)(p + (size_t)c * 8 + 4);
    a.x -= L; a.y -= L; a.z -= L; a.w -= L;
    b.x -= L; b.y -= L; b.z -= L; b.w -= L;
    *(f4v*)(p + (size_t)c * 8) = a;
    *(f4v*)(p + (size_t)c * 8 + 4) = b;
  }
}

extern "C" void kernel_launch(void* const* d_in, const int* in_sizes, int n_in,
                              void* d_out, int out_size, void* d_ws, size_t ws_size,
                              hipStream_t stream) {
  (void)in_sizes; (void)n_in; (void)out_size; (void)ws_size;
  const float* target = (const float*)d_in[0];
  const float* inp    = (const float*)d_in[1];
  const float* posf   = (const float*)d_in[2];
  const float* encs   = (const float*)d_in[3];
  const float* enco   = (const float*)d_in[4];
  const float* Wih    = (const float*)d_in[5];
  const float* Whh    = (const float*)d_in[6];
  const float* bih    = (const float*)d_in[7];
  const float* bhh    = (const float*)d_in[8];
  const float* Winw   = (const float*)d_in[9];
  const float* Winb   = (const float*)d_in[10];
  const float* Woutw  = (const float*)d_in[11];
  const float* Woutb  = (const float*)d_in[12];

  char* ws = (char*)d_ws;
  ushort* X      = (ushort*)(ws);              // 2048*640  bf16 = 0x280000
  float*  gi     = (float*)(ws + 0x280000);    // 2048*768  fp32 = 0x600000
  ushort* feat   = (ushort*)(ws + 0x880000);   // 2048*768  bf16 = 0x300000
  ushort* Whh_b  = (ushort*)(ws + 0xB80000);   // 768*256   bf16 = 0x60000
  ushort* Winw_b = (ushort*)(ws + 0xBE0000);   // 512*256   bf16 = 0x40000
  float* hs    = (float*)d_out;                // [16384 hs][2048*32000 logits]
  float* logits = hs + 16384;

  k_cvt<<<320, 256, 0, stream>>>(Whh, Winw, Whh_b, Winw_b);
  k_gather<<<2048, 256, 0, stream>>>(target, inp, posf, encs, X);
  k_gemm_bt<false><<<dim3(16, 6), 256, 0, stream>>>(X, Wih, bih, gi, 768, 640);
  k_recur<<<64, 1024, 0, stream>>>(gi, enco, Whh_b, bhh, Winw_b, Winb, feat, hs);
  k_gemm_bt<true><<<dim3(16, 250), 256, 0, stream>>>(feat, Woutw, Woutb, logits,
                                                     32000, 768);
  k_logsm<<<2048, 256, 0, stream>>>(logits);
}